// Round 18
// baseline (84.415 us; speedup 1.0000x reference)
//
#include <hip/hip_runtime.h>
#include <math.h>

// Problem constants
#define B_ 64
#define N_ 128
#define D_ 128
#define BN_ 8192
#define NG_ 50
#define CUTOFF_ 10.0f

typedef __attribute__((ext_vector_type(8))) short short8v;   // 8 bf16
typedef __attribute__((ext_vector_type(4))) float f32x4;
#define MFMA16 __builtin_amdgcn_mfma_f32_16x16x32_bf16

__device__ __forceinline__ float bf2f(unsigned short h) {
    return __builtin_bit_cast(float, ((unsigned int)h) << 16);
}
__device__ __forceinline__ unsigned short f2bf(float f) {
    unsigned int u = __builtin_bit_cast(unsigned int, f);
    return (unsigned short)((u + 0x7FFFu + ((u >> 16) & 1u)) >> 16);
}
__device__ __forceinline__ void splitbf(float x, unsigned short& h, unsigned short& l) {
    h = f2bf(x);
    l = f2bf(x - bf2f(h));
}
__device__ __forceinline__ void gl_lds(const void* g, void* l) {
    __builtin_amdgcn_global_load_lds(
        (const __attribute__((address_space(1))) void*)g,
        (__attribute__((address_space(3))) void*)l, 16, 0, 0);
}

// ---------------------------------------------------------------------------
// setup_k: weight prep [0,513) | copy [513,642) | RMSNorm [642,2690) |
//          adjacency [2690,3714).
__global__ __launch_bounds__(256) void setup_k(
        const float* __restrict__ x, const float* __restrict__ norm_w,
        const float* __restrict__ pos, const int* __restrict__ mi,
        const float* __restrict__ lin_w, const float* __restrict__ lin_b,
        const float* __restrict__ w1, const float* __restrict__ w2,
        const float* __restrict__ b2, const float* __restrict__ in_proj,
        const float* __restrict__ xpw, const float* __restrict__ dtw,
        const float* __restrict__ out_proj,
        unsigned short* __restrict__ w1Th, unsigned short* __restrict__ w1Tl,
        unsigned short* __restrict__ WdTh, unsigned short* __restrict__ WdTl,
        unsigned short* __restrict__ opTh, unsigned short* __restrict__ opTl,
        unsigned short* __restrict__ WfTh, unsigned short* __restrict__ WfTl,
        float* __restrict__ bfv,
        float* __restrict__ x1f, unsigned short* __restrict__ x1h,
        unsigned short* __restrict__ x1l,
        unsigned short* __restrict__ adjh, unsigned short* __restrict__ adjl,
        unsigned short* __restrict__ emh, float* __restrict__ rdeg,
        float* __restrict__ out) {
    int blk = blockIdx.x, t = threadIdx.x;
    if (blk < 513) {
        if (blk < 128) {
            if (t < 128) {
                unsigned short h, l;
                splitbf(w1[blk * 128 + t], h, l);
                w1Th[t * 128 + blk] = h; w1Tl[t * 128 + blk] = l;
            }
        } else if (blk < 256) {
            int m = blk - 128;
            if (t < 128) {
                float s = 0.0f;
                #pragma unroll
                for (int r = 0; r < 8; r++) s = fmaf(xpw[m * 12 + r], dtw[r * 128 + t], s);
                unsigned short h, l; splitbf(s, h, l);
                WdTh[t * 128 + m] = h; WdTl[t * 128 + m] = l;
            }
        } else if (blk < 384) {
            int k = blk - 256;
            if (t < 128) {
                unsigned short h, l;
                splitbf(out_proj[k * 128 + t], h, l);
                opTh[t * 128 + k] = h; opTl[t * 128 + k] = l;
            }
        } else if (blk < 512) {
            int k = blk - 384;
            float s = 0.0f;
            #pragma unroll 8
            for (int j = 0; j < 128; j++) s = fmaf(w2[k * 128 + j], in_proj[j * 256 + t], s);
            unsigned short h, l; splitbf(s, h, l);
            WfTh[t * 128 + k] = h; WfTl[t * 128 + k] = l;
        } else {
            float s = 0.0f;
            #pragma unroll 8
            for (int j = 0; j < 128; j++) s = fmaf(b2[j], in_proj[j * 256 + t], s);
            bfv[t] = s;
        }
    } else if (blk < 642) {
        int idx = (blk - 513) * 256 + t;
        if (idx < BN_ * 3) out[(size_t)BN_ * D_ + idx] = pos[idx];
        if (idx < BN_) out[(size_t)BN_ * D_ + BN_ * 3 + idx] = (float)mi[idx];
    } else if (blk < 2690) {
        int rblk = blk - 642;
        int wv = t >> 6, ln = t & 63;
        int row = rblk * 4 + wv;
        const float2* xr = reinterpret_cast<const float2*>(x) + (size_t)row * 64;
        float2 v = xr[ln];
        float s = fmaf(v.x, v.x, v.y * v.y);
        #pragma unroll
        for (int o = 32; o > 0; o >>= 1) s += __shfl_down(s, o, 64);
        float tot = __shfl(s, 0, 64);
        float r = rsqrtf(tot * (1.0f / D_) + 1e-5f);
        float2 wv2 = reinterpret_cast<const float2*>(norm_w)[ln];
        float o0 = v.x * r * wv2.x, o1 = v.y * r * wv2.y;
        reinterpret_cast<float2*>(x1f)[(size_t)row * 64 + ln] = make_float2(o0, o1);
        unsigned short h0, l0, h1, l1;
        splitbf(o0, h0, l0); splitbf(o1, h1, l1);
        reinterpret_cast<ushort2*>(x1h)[(size_t)row * 64 + ln] = make_ushort2(h0, h1);
        reinterpret_cast<ushort2*>(x1l)[(size_t)row * 64 + ln] = make_ushort2(l0, l1);
    } else {
        __shared__ float px[N_], py[N_], pz[N_];
        __shared__ float lw[NG_];
        __shared__ int degs[8];
        int ablk = blk - 2690;
        int bx = ablk & 15, b = ablk >> 4;
        if (t < N_) {
            const float* p = pos + (size_t)(b * N_ + t) * 3;
            px[t] = p[0]; py[t] = p[1]; pz[t] = p[2];
        } else if (t - N_ < NG_) {
            lw[t - N_] = lin_w[t - N_];
        }
        if (t >= 248) degs[t - 248] = 0;
        __syncthreads();
        float linb = lin_b[0];
        int j = t & 127;
        int il = t >> 7;
        const float DEL = 10.0f / 49.0f;
        const float COEFF = -0.5f / (DEL * DEL);
        #pragma unroll
        for (int p = 0; p < 4; p++) {
            int i = bx * 8 + p * 2 + il;
            float dx = px[i] - px[j], dy = py[i] - py[j], dz = pz[i] - pz[j];
            float d2 = dx * dx + dy * dy + dz * dz;
            float dist = (i == j) ? 1.0f : sqrtf(d2);
            bool edge = (i != j) && (dist < CUTOFF_);
            float val = 0.0f;
            if (edge) {
                int g0 = (int)ceilf((dist - 1.75f) / DEL); if (g0 < 0) g0 = 0;
                int g1 = (int)floorf((dist + 1.75f) / DEL); if (g1 > NG_ - 1) g1 = NG_ - 1;
                float dm = dist - (float)g0 * DEL;
                float tg = expf(COEFF * dm * dm);
                float ug = expf(COEFF * DEL * (DEL - 2.0f * dm));
                float s = linb;
                for (int g = g0; g <= g1; g++) {
                    s = fmaf(lw[g], tg, s);
                    tg *= ug;
                    ug *= 0.36787944117144233f;   // e^{-1}
                }
                val = s;
            }
            size_t idx = ((size_t)b * N_ + i) * N_ + j;
            unsigned short h, l; splitbf(val, h, l);
            adjh[idx] = h; adjl[idx] = l;
            emh[idx] = edge ? 0x3F80 : 0;
            unsigned long long msk = __ballot(edge);
            if ((t & 63) == 0) atomicAdd(&degs[p * 2 + il], __popcll(msk));
        }
        __syncthreads();
        if (t < 8) {
            int dg = degs[t];
            rdeg[(size_t)b * N_ + bx * 8 + t] = 1.0f / (float)(dg > 0 ? dg : 1);
        }
    }
}

// ---------------------------------------------------------------------------
// staging/GEMM helpers (512 threads)
__device__ __forceinline__ void st128(char* dst, const char* g, int tid) {
    #pragma unroll
    for (int i = 0; i < 4; i++) {
        int s = tid + i * 512;
        int row = s >> 4, inner = s & 15;
        gl_lds(g + row * 256 + ((inner * 16) ^ ((row & 7) << 4)), dst + s * 16);
    }
}
__device__ __forceinline__ void stA48(char* dst, const char* g, int r0, int tid) {
    #pragma unroll
    for (int i = 0; i < 2; i++) {
        int s = tid + i * 512;
        if (s < 768) {
            int lr = s >> 4, inner = s & 15;
            int srow = r0 - 16 + lr; if (srow < 0) srow = 0;
            gl_lds(g + srow * 256 + ((inner * 16) ^ ((lr & 7) << 4)), dst + s * 16);
        }
    }
}
template <int NRF>
__device__ __forceinline__ void fpass(const char* sm, int ah, int al, int bh, int bl,
                                      int w, int l, f32x4 (&acc)[NRF]) {
    int rlow = l & 15, khi = (l >> 4) * 16;
    int nB = w * 16 + rlow;
    int nkey = (nB & 7) << 4;
    #pragma unroll
    for (int kb = 0; kb < 4; kb++) {
        int kbyte = kb * 64 + khi;
        short8v bhv = *(const short8v*)(sm + bh + nB * 256 + (kbyte ^ nkey));
        short8v blv = *(const short8v*)(sm + bl + nB * 256 + (kbyte ^ nkey));
        #pragma unroll
        for (int rf = 0; rf < NRF; rf++) {
            int ra = rf * 16 + rlow;
            int ao = ra * 256 + (kbyte ^ ((ra & 7) << 4));
            short8v ahv = *(const short8v*)(sm + ah + ao);
            short8v alv = *(const short8v*)(sm + al + ao);
            acc[rf] = MFMA16(ahv, bhv, acc[rf], 0, 0, 0);
            acc[rf] = MFMA16(ahv, blv, acc[rf], 0, 0, 0);
            acc[rf] = MFMA16(alv, bhv, acc[rf], 0, 0, 0);
        }
    }
}

// ---------------------------------------------------------------------------
// hagg_k: per-batch fused h-GEMM + agg-GEMM.
// Block b: h = relu(x1[b] @ w1 + b1) (128x128, in LDS as hT planes), then
// agg = (em[b] @ h) * rdeg -> agg planes global.  64 blocks x 512 thr, 128KB.
__global__ __launch_bounds__(512) void hagg_k(
        const unsigned short* __restrict__ x1h, const unsigned short* __restrict__ x1l,
        const unsigned short* __restrict__ w1Th, const unsigned short* __restrict__ w1Tl,
        const float* __restrict__ b1,
        const unsigned short* __restrict__ emh, const float* __restrict__ rdeg,
        unsigned short* __restrict__ aggh, unsigned short* __restrict__ aggl) {
    __shared__ __align__(16) char smb[131072];
    const int AH = 0, AL = 32768, BH = 65536, BL = 98304;
    int b = blockIdx.x, tid = threadIdx.x;
    int w = tid >> 6, l = tid & 63;
    int rlow = l & 15, khi = (l >> 4) * 16, qrow = (l >> 4) * 4;
    int colg = w * 16 + rlow;
    int ckey = (colg & 7) << 4;

    // stage x1[b] planes + w1T planes
    st128(smb + AH, (const char*)x1h + (size_t)b * 32768, tid);
    st128(smb + AL, (const char*)x1l + (size_t)b * 32768, tid);
    st128(smb + BH, (const char*)w1Th, tid);
    st128(smb + BL, (const char*)w1Tl, tid);
    __syncthreads();

    // h-GEMM: 128 rows x 128 cols (8 waves as 8 col-units, NRF=8)
    f32x4 acc[8];
    #pragma unroll
    for (int i = 0; i < 8; i++) acc[i] = (f32x4){0.f, 0.f, 0.f, 0.f};
    fpass<8>(smb, AH, AL, BH, BL, w, l, acc);
    __syncthreads();   // all x1/w1 reads complete

    // epilogue: relu+bias -> hT planes into AH/AL (swizzled [n][k])
    {
        float bb = b1[colg];
        #pragma unroll
        for (int rf = 0; rf < 8; rf++) {
            int row0 = rf * 16 + qrow;
            unsigned short hh[4], ll[4];
            #pragma unroll
            for (int q = 0; q < 4; q++) {
                float t = fmaxf(acc[rf][q] + bb, 0.0f);
                splitbf(t, hh[q], ll[q]);
            }
            int byo = (row0 * 2) ^ ckey;
            *(ushort4*)(smb + AH + colg * 256 + byo) = make_ushort4(hh[0], hh[1], hh[2], hh[3]);
            *(ushort4*)(smb + AL + colg * 256 + byo) = make_ushort4(ll[0], ll[1], ll[2], ll[3]);
        }
    }
    // stage em[b] hi plane into BH (w1T reads done)
    st128(smb + BH, (const char*)emh + (size_t)b * 32768, tid);
    __syncthreads();

    // agg-GEMM: A = em (hi only), B = hT planes (2-term, mgemm EPI=2 order)
    f32x4 ag[8];
    #pragma unroll
    for (int i = 0; i < 8; i++) ag[i] = (f32x4){0.f, 0.f, 0.f, 0.f};
    {
        int nB = colg;
        int nkey = ckey;
        #pragma unroll
        for (int kb = 0; kb < 4; kb++) {
            int kbyte = kb * 64 + khi;
            short8v bh_ = *(const short8v*)(smb + AH + nB * 256 + (kbyte ^ nkey));
            short8v bl_ = *(const short8v*)(smb + AL + nB * 256 + (kbyte ^ nkey));
            #pragma unroll
            for (int rf = 0; rf < 8; rf++) {
                int ra = rf * 16 + rlow;
                short8v ae = *(const short8v*)(smb + BH + ra * 256 + (kbyte ^ ((ra & 7) << 4)));
                ag[rf] = MFMA16(ae, bh_, ag[rf], 0, 0, 0);
                ag[rf] = MFMA16(ae, bl_, ag[rf], 0, 0, 0);
            }
        }
    }
    // epilogue: scale by rdeg[row] -> agg planes global [b][row][col]
    #pragma unroll
    for (int rf = 0; rf < 8; rf++) {
        int row0 = rf * 16 + qrow;
        #pragma unroll
        for (int q = 0; q < 4; q++) {
            int row = row0 + q;
            float t = ag[rf][q] * rdeg[b * 128 + row];
            unsigned short h, lo; splitbf(t, h, lo);
            size_t g = (size_t)b * 16384 + (size_t)row * 128 + colg;
            aggh[g] = h;
            aggl[g] = lo;
        }
    }
}

// ---------------------------------------------------------------------------
// fused_k: per (batch, 32-row group): xr GEMM, conv1d+silu+bc, delta GEMM,
// dp GEMM.  grid 256 x 512, 160KB LDS.
__global__ __launch_bounds__(512, 2) void fused_k(
        const unsigned short* __restrict__ aggh, const unsigned short* __restrict__ aggl,
        const unsigned short* __restrict__ WfTh, const unsigned short* __restrict__ WfTl,
        const float* __restrict__ bfv,
        const float* __restrict__ conv_w, const float* __restrict__ conv_b,
        const float* __restrict__ xpw,
        const unsigned short* __restrict__ WdTh, const unsigned short* __restrict__ WdTl,
        const float* __restrict__ dtb,
        const unsigned short* __restrict__ adjh, const unsigned short* __restrict__ adjl,
        float* __restrict__ resT, float* __restrict__ xcT,
        float* __restrict__ bcT, float* __restrict__ dpT) {
    __shared__ __align__(16) char sm[163840];
    const int AH = 0, AL = 12288, XM = 24576, BH = 49152, BL = 81920,
              XCH = 114688, XCL = 122880, DH = 131072, DL = 139264, XCF = 147456;
    int blk = blockIdx.x, tid = threadIdx.x;
    int b = blk >> 2, r0 = (blk & 3) * 32;
    int w = tid >> 6, l = tid & 63;
    int rlow = l & 15, qrow = (l >> 4) * 4;

    stA48(sm + AH, (const char*)aggh + (size_t)b * 32768, r0, tid);
    stA48(sm + AL, (const char*)aggl + (size_t)b * 32768, r0, tid);
    st128(sm + BH, (const char*)WfTh, tid);
    st128(sm + BL, (const char*)WfTl, tid);
    __syncthreads();

    f32x4 acc[3] = {{0.f,0.f,0.f,0.f},{0.f,0.f,0.f,0.f},{0.f,0.f,0.f,0.f}};
    fpass<3>(sm, AH, AL, BH, BL, w, l, acc);
    __syncthreads();
    st128(sm + BH, (const char*)WfTh + 32768, tid);
    st128(sm + BL, (const char*)WfTl + 32768, tid);
    {
        int colg = w * 16 + rlow;
        float bb = bfv[colg];
        #pragma unroll
        for (int rf = 0; rf < 3; rf++) {
            #pragma unroll
            for (int q = 0; q < 4; q++) {
                int lr = rf * 16 + qrow + q;
                *(float*)(sm + XM + lr * 512 + ((colg * 4) ^ ((lr & 7) << 4))) =
                    acc[rf][q] + bb;
            }
        }
    }
    __syncthreads();

    f32x4 acc2[3] = {{0.f,0.f,0.f,0.f},{0.f,0.f,0.f,0.f},{0.f,0.f,0.f,0.f}};
    fpass<3>(sm, AH, AL, BH, BL, w, l, acc2);
    {
        int colg = w * 16 + rlow;
        float bb = bfv[128 + colg];
        #pragma unroll
        for (int rf = 1; rf < 3; rf++) {
            int lr0 = rf * 16 + qrow;
            int tt = r0 + lr0 - 16;
            float v[4];
            #pragma unroll
            for (int q = 0; q < 4; q++) {
                float rs = acc2[rf][q] + bb;
                v[q] = rs / (1.0f + expf(-rs));
            }
            *reinterpret_cast<float4*>(resT + ((size_t)b * 128 + colg) * 128 + tt) =
                make_float4(v[0], v[1], v[2], v[3]);
        }
    }
    __syncthreads();

    st128(sm + BH, (const char*)WdTh, tid);
    st128(sm + BL, (const char*)WdTl, tid);
    {
        int ot = tid >> 4, dg = tid & 15;
        float pc0 = 0, pc1 = 0, pc2 = 0, pc3 = 0;
        #pragma unroll
        for (int k = 0; k < 8; k++) {
            int d = dg * 8 + k;
            float accv = conv_b[d];
            #pragma unroll
            for (int jj = 0; jj < 4; jj++) {
                int tt = r0 + ot + jj - 3;
                if (tt >= 0) {
                    int lr = ot + jj - 3 + 16;
                    float xv = *(const float*)(sm + XM + lr * 512 +
                                               ((d * 4) ^ ((lr & 7) << 4)));
                    accv = fmaf(xv, conv_w[d * 4 + jj], accv);
                }
            }
            float xc = accv / (1.0f + expf(-accv));   // silu
            unsigned short hh, ll; splitbf(xc, hh, ll);
            int pb = ot * 256 + ((d * 2) ^ ((ot & 7) << 4));
            *(unsigned short*)(sm + XCH + pb) = hh;
            *(unsigned short*)(sm + XCL + pb) = ll;
            *(float*)(sm + XCF + ot * 512 + ((d * 4) ^ ((ot & 7) << 4))) = xc;
            float4 xw = *(const float4*)(xpw + d * 12 + 8);
            pc0 = fmaf(xc, xw.x, pc0); pc1 = fmaf(xc, xw.y, pc1);
            pc2 = fmaf(xc, xw.z, pc2); pc3 = fmaf(xc, xw.w, pc3);
        }
        #pragma unroll
        for (int m = 1; m < 16; m <<= 1) {
            pc0 += __shfl_xor(pc0, m, 64);
            pc1 += __shfl_xor(pc1, m, 64);
            pc2 += __shfl_xor(pc2, m, 64);
            pc3 += __shfl_xor(pc3, m, 64);
        }
        if (dg < 4) {
            float pv = dg == 0 ? pc0 : dg == 1 ? pc1 : dg == 2 ? pc2 : pc3;
            bcT[(size_t)b * 512 + dg * 128 + r0 + ot] = pv;
        }
    }
    __syncthreads();

    {
        int d = tid & 127, tg = tid >> 7;
        float v[8];
        #pragma unroll
        for (int k = 0; k < 8; k++) {
            int ot = tg * 8 + k;
            v[k] = *(const float*)(sm + XCF + ot * 512 + ((d * 4) ^ ((ot & 7) << 4)));
        }
        float* dst = xcT + ((size_t)b * 128 + d) * 128 + r0 + tg * 8;
        *reinterpret_cast<float4*>(dst) = make_float4(v[0], v[1], v[2], v[3]);
        *reinterpret_cast<float4*>(dst + 4) = make_float4(v[4], v[5], v[6], v[7]);
    }

    f32x4 dacc[2] = {{0.f,0.f,0.f,0.f},{0.f,0.f,0.f,0.f}};
    fpass<2>(sm, XCH, XCL, BH, BL, w, l, dacc);
    {
        int colg = w * 16 + rlow;
        float db = dtb[colg];
        #pragma unroll
        for (int rf = 0; rf < 2; rf++) {
            #pragma unroll
            for (int q = 0; q < 4; q++) {
                int lr = rf * 16 + qrow + q;
                float t = dacc[rf][q] + db;
                t = fmaxf(t, 0.0f) + log1pf(expf(-fabsf(t)));
                unsigned short hh, ll; splitbf(t, hh, ll);
                int pb = lr * 256 + ((colg * 2) ^ ((lr & 7) << 4));
                *(unsigned short*)(sm + DH + pb) = hh;
                *(unsigned short*)(sm + DL + pb) = ll;
            }
        }
    }
    __syncthreads();

    st128(sm + BH, (const char*)adjh + (size_t)b * 32768, tid);
    st128(sm + BL, (const char*)adjl + (size_t)b * 32768, tid);
    __syncthreads();
    f32x4 pacc[2] = {{0.f,0.f,0.f,0.f},{0.f,0.f,0.f,0.f}};
    fpass<2>(sm, DH, DL, BH, BL, w, l, pacc);
    {
        int colg = w * 16 + rlow;
        #pragma unroll
        for (int rf = 0; rf < 2; rf++) {
            int lr0 = rf * 16 + qrow;
            *reinterpret_cast<float4*>(dpT + ((size_t)b * 128 + colg) * 128 + r0 + lr0) =
                make_float4(pacc[rf][0], pacc[rf][1], pacc[rf][2], pacc[rf][3]);
        }
    }
}

// ---------------------------------------------------------------------------
// scanout_k: shfl-free chunked LDS scan + fused out-GEMM (proven R17).
__global__ __launch_bounds__(256) void scanout_k(
        const float* __restrict__ dpT, const float* __restrict__ xcT,
        const float* __restrict__ bcT, const float* __restrict__ resT,
        const float* __restrict__ A_log, const float* __restrict__ Dpar,
        const unsigned short* __restrict__ opTh, const unsigned short* __restrict__ opTl,
        const float* __restrict__ x1f, float* __restrict__ out) {
    __shared__ __align__(16) char smb[116736];
    float* lds = (float*)smb;
    float* bcl = (float*)(smb + 49152);
    const int YH = 51200, YL = 83968;
    int b = blockIdx.x;
    int t = threadIdx.x;
    if (t < 128) {
        float4 v = reinterpret_cast<const float4*>(bcT + (size_t)b * 512)[t];
        *reinterpret_cast<float4*>(bcl + t * 4) = v;
    }
    float a1 = 0.f, a2 = 0.f, Dp = 0.f;
    if (t < 128) {
        a1 = -expf(A_log[t * 2]);
        a2 = -expf(A_log[t * 2 + 1]);
        Dp = Dpar[t];
    }
    float h1 = 0.0f, h2 = 0.0f;
    const float4* dp4 = reinterpret_cast<const float4*>(dpT + (size_t)b * 16384);
    const float4* xc4 = reinterpret_cast<const float4*>(xcT + (size_t)b * 16384);
    const float4* rr4 = reinterpret_cast<const float4*>(resT + (size_t)b * 16384);
    for (int c = 0; c < 4; c++) {
        __syncthreads();
        #pragma unroll
        for (int k = 0; k < 4; k++) {
            int q = t + k * 256;
            int dd = q >> 3, tq = q & 7;
            int gidx = dd * 32 + c * 8 + tq;
            float4 vd = dp4[gidx], vx = xc4[gidx], vr = rr4[gidx];
            #pragma unroll
            for (int j = 0; j < 4; j++) {
                int tp = tq * 4 + j;
                int sw = dd ^ tp;
                float fd = (j == 0) ? vd.x : (j == 1) ? vd.y : (j == 2) ? vd.z : vd.w;
                float fx = (j == 0) ? vx.x : (j == 1) ? vx.y : (j == 2) ? vx.z : vx.w;
                float fr = (j == 0) ? vr.x : (j == 1) ? vr.y : (j == 2) ? vr.z : vr.w;
                lds[tp * 128 + sw] = fd;
                lds[4096 + tp * 128 + sw] = fx;
                lds[8192 + tp * 128 + sw] = fr;
            }
        }
        __syncthreads();
        if (t < 128) {
            #pragma unroll 8
            for (int tp = 0; tp < 32; tp++) {
                int sw = t ^ tp;
                float dpv = lds[tp * 128 + sw];
                float xcv = lds[4096 + tp * 128 + sw];
                float rv  = lds[8192 + tp * 128 + sw];
                int tg = c * 32 + tp;
                float bm0 = bcl[tg], bm1 = bcl[128 + tg];
                float cm0 = bcl[256 + tg], cm1 = bcl[384 + tg];
                float e1 = expf(dpv * a1), e2 = expf(dpv * a2);
                float bu = dpv * xcv;
                h1 = fmaf(e1, h1, bu * bm0);
                h2 = fmaf(e2, h2, bu * bm1);
                float y = fmaf(h1, cm0, h2 * cm1);
                float yv = fmaf(xcv, Dp, y) * rv;
                unsigned short hh, ll; splitbf(yv, hh, ll);
                int byo = (t * 2) ^ ((tg & 7) << 4);
                *(unsigned short*)(smb + YH + tg * 256 + byo) = hh;
                *(unsigned short*)(smb + YL + tg * 256 + byo) = ll;
            }
        }
    }
    __syncthreads();

    int w = t >> 6, l = t & 63;
    int rlow = l & 15, kb_lane = (l >> 4) * 16;
    int nB = w * 16 + rlow;
    int nswz = (nB & 7) << 4;
    for (int cu = 0; cu < 2; cu++) {
        #pragma unroll
        for (int i = 0; i < 4; i++) {
            int s = t + i * 256;
            int row = s >> 4, inner = s & 15;
            int gb = (inner * 16) ^ ((row & 7) << 4);
            size_t gsrc = (size_t)(cu * 64 + row) * 256 + gb;
            gl_lds((const char*)opTh + gsrc, smb + s * 16);
            gl_lds((const char*)opTl + gsrc, smb + 16384 + s * 16);
        }
        __syncthreads();
        int colg = cu * 64 + nB;
        for (int ru = 0; ru < 4; ru++) {
            f32x4 acc[2] = {{0.f, 0.f, 0.f, 0.f}, {0.f, 0.f, 0.f, 0.f}};
            #pragma unroll
            for (int kb = 0; kb < 4; kb++) {
                int kbyte = kb * 64 + kb_lane;
                short8v bh = *(const short8v*)(smb + nB * 256 + (kbyte ^ nswz));
                short8v bl = *(const short8v*)(smb + 16384 + nB * 256 + (kbyte ^ nswz));
                #pragma unroll
                for (int rf = 0; rf < 2; rf++) {
                    int ra = ru * 32 + rf * 16 + rlow;
                    int aswz = (ra & 7) << 4;
                    short8v ah = *(const short8v*)(smb + YH + ra * 256 + (kbyte ^ aswz));
                    acc[rf] = MFMA16(ah, bh, acc[rf], 0, 0, 0);
                    acc[rf] = MFMA16(ah, bl, acc[rf], 0, 0, 0);
                    short8v al_ = *(const short8v*)(smb + YL + ra * 256 + (kbyte ^ aswz));
                    acc[rf] = MFMA16(al_, bh, acc[rf], 0, 0, 0);
                }
            }
            #pragma unroll
            for (int rf = 0; rf < 2; rf++) {
                int row0 = ru * 32 + rf * 16 + (l >> 4) * 4;
                #pragma unroll
                for (int q = 0; q < 4; q++) {
                    int row = row0 + q;
                    float tv = acc[rf][q];
                    tv = isfinite(tv) ? tv : 0.0f;
                    size_t g = (size_t)(b * 128 + row) * 128 + colg;
                    out[g] = tv + x1f[g];
                }
            }
        }
        __syncthreads();
    }
}

// ---------------------------------------------------------------------------
extern "C" void kernel_launch(void* const* d_in, const int* in_sizes, int n_in,
                              void* d_out, int out_size, void* d_ws, size_t ws_size,
                              hipStream_t stream) {
    const float* x        = (const float*)d_in[0];
    const float* pos      = (const float*)d_in[1];
    const int*   mi       = (const int*)d_in[2];
    const float* norm_w   = (const float*)d_in[4];
    const float* w1       = (const float*)d_in[5];
    const float* b1       = (const float*)d_in[6];
    const float* w2       = (const float*)d_in[7];
    const float* b2       = (const float*)d_in[8];
    const float* lin_w    = (const float*)d_in[9];
    const float* lin_b    = (const float*)d_in[10];
    const float* in_proj  = (const float*)d_in[11];
    const float* conv_w   = (const float*)d_in[12];
    const float* conv_b   = (const float*)d_in[13];
    const float* xpw      = (const float*)d_in[14];
    const float* dtw      = (const float*)d_in[15];
    const float* dtb      = (const float*)d_in[16];
    const float* A_log    = (const float*)d_in[17];
    const float* Dpar     = (const float*)d_in[18];
    const float* out_proj = (const float*)d_in[19];

    float* out = (float*)d_out;
    char* base = (char*)d_ws;
    const size_t MB = 1u << 20;
    const size_t PL = 1048576;            // elements per bf16 plane

    float* x1f  = (float*)(base);                      // 4MB
    float* resT = (float*)(base + 8 * MB);             // 4MB  [b][d][t]
    float* dpT  = (float*)(base + 12 * MB);            // 4MB  [b][d][t]
    float* xcT  = (float*)(base + 16 * MB);            // 4MB  [b][d][t]
    float* bcT  = (float*)(base + 20 * MB);            // 128KB [b][4][t]
    float* rdeg = (float*)(base + 20 * MB + 131072);   // 32KB

    unsigned short* P = (unsigned short*)(base + 21 * MB);
    unsigned short* x1h  = P +  0 * PL;
    unsigned short* x1l  = P +  1 * PL;
    unsigned short* aggh = P +  4 * PL;
    unsigned short* aggl = P +  5 * PL;
    unsigned short* adjh = P + 12 * PL;   // symmetric => also B^T
    unsigned short* adjl = P + 13 * PL;
    unsigned short* emh  = P + 14 * PL;

    unsigned short* W = (unsigned short*)(base + 52 * MB);
    unsigned short* w1Th = W;
    unsigned short* w1Tl = W + 16384;
    unsigned short* WdTh = W + 2 * 16384;
    unsigned short* WdTl = W + 3 * 16384;
    unsigned short* opTh = W + 4 * 16384;
    unsigned short* opTl = W + 5 * 16384;
    unsigned short* WfTh = W + 6 * 16384;          // [256][128]
    unsigned short* WfTl = WfTh + 32768;
    float* bfv = (float*)(WfTl + 32768);

    // 1. setup: weights + copy + rmsnorm + adjacency
    setup_k<<<3714, 256, 0, stream>>>(x, norm_w, pos, mi, lin_w, lin_b,
                                      w1, w2, b2, in_proj, xpw, dtw, out_proj,
                                      w1Th, w1Tl, WdTh, WdTl, opTh, opTl, WfTh, WfTl,
                                      bfv, x1f, x1h, x1l, adjh, adjl, emh, rdeg, out);
    // 2. fused h-GEMM + agg-GEMM (per batch)
    hagg_k<<<B_, 512, 0, stream>>>(x1h, x1l, w1Th, w1Tl, b1, emh, rdeg, aggh, aggl);
    // 3. fused middle: xr + conv/silu/bc + delta + dp
    fused_k<<<256, 512, 0, stream>>>(aggh, aggl, WfTh, WfTl, bfv,
                                     conv_w, conv_b, xpw, WdTh, WdTl, dtb,
                                     adjh, adjl, resT, xcT, bcT, dpT);
    // 4. scan + fused out-GEMM -> d_out
    scanout_k<<<B_, 256, 0, stream>>>(dpT, xcT, bcT, resT, A_log, Dpar,
                                      opTh, opTl, x1f, out);
}

// Round 19
// 83.554 us; speedup vs baseline: 1.0103x; 1.0103x over previous
//
#include <hip/hip_runtime.h>
#include <math.h>

// Problem constants
#define B_ 64
#define N_ 128
#define D_ 128
#define BN_ 8192
#define NG_ 50
#define CUTOFF_ 10.0f

typedef __attribute__((ext_vector_type(8))) short short8v;   // 8 bf16
typedef __attribute__((ext_vector_type(4))) float f32x4;
#define MFMA16 __builtin_amdgcn_mfma_f32_16x16x32_bf16

__device__ __forceinline__ float bf2f(unsigned short h) {
    return __builtin_bit_cast(float, ((unsigned int)h) << 16);
}
__device__ __forceinline__ unsigned short f2bf(float f) {
    unsigned int u = __builtin_bit_cast(unsigned int, f);
    return (unsigned short)((u + 0x7FFFu + ((u >> 16) & 1u)) >> 16);
}
__device__ __forceinline__ void splitbf(float x, unsigned short& h, unsigned short& l) {
    h = f2bf(x);
    l = f2bf(x - bf2f(h));
}
__device__ __forceinline__ void gl_lds(const void* g, void* l) {
    __builtin_amdgcn_global_load_lds(
        (const __attribute__((address_space(1))) void*)g,
        (__attribute__((address_space(3))) void*)l, 16, 0, 0);
}

// ---------------------------------------------------------------------------
// setup_k: weight prep [0,513) | copy [513,642) | RMSNorm [642,2690) |
//          adjacency [2690,3714).
__global__ __launch_bounds__(256) void setup_k(
        const float* __restrict__ x, const float* __restrict__ norm_w,
        const float* __restrict__ pos, const int* __restrict__ mi,
        const float* __restrict__ lin_w, const float* __restrict__ lin_b,
        const float* __restrict__ w1, const float* __restrict__ w2,
        const float* __restrict__ b2, const float* __restrict__ in_proj,
        const float* __restrict__ xpw, const float* __restrict__ dtw,
        const float* __restrict__ out_proj,
        unsigned short* __restrict__ w1Th, unsigned short* __restrict__ w1Tl,
        unsigned short* __restrict__ WdTh, unsigned short* __restrict__ WdTl,
        unsigned short* __restrict__ opTh, unsigned short* __restrict__ opTl,
        unsigned short* __restrict__ WfTh, unsigned short* __restrict__ WfTl,
        float* __restrict__ bfv,
        float* __restrict__ x1f, unsigned short* __restrict__ x1h,
        unsigned short* __restrict__ x1l,
        unsigned short* __restrict__ adjh, unsigned short* __restrict__ adjl,
        unsigned short* __restrict__ emh, float* __restrict__ rdeg,
        float* __restrict__ out) {
    int blk = blockIdx.x, t = threadIdx.x;
    if (blk < 513) {
        if (blk < 128) {
            if (t < 128) {
                unsigned short h, l;
                splitbf(w1[blk * 128 + t], h, l);
                w1Th[t * 128 + blk] = h; w1Tl[t * 128 + blk] = l;
            }
        } else if (blk < 256) {
            int m = blk - 128;
            if (t < 128) {
                float s = 0.0f;
                #pragma unroll
                for (int r = 0; r < 8; r++) s = fmaf(xpw[m * 12 + r], dtw[r * 128 + t], s);
                unsigned short h, l; splitbf(s, h, l);
                WdTh[t * 128 + m] = h; WdTl[t * 128 + m] = l;
            }
        } else if (blk < 384) {
            int k = blk - 256;
            if (t < 128) {
                unsigned short h, l;
                splitbf(out_proj[k * 128 + t], h, l);
                opTh[t * 128 + k] = h; opTl[t * 128 + k] = l;
            }
        } else if (blk < 512) {
            int k = blk - 384;
            float s = 0.0f;
            #pragma unroll 8
            for (int j = 0; j < 128; j++) s = fmaf(w2[k * 128 + j], in_proj[j * 256 + t], s);
            unsigned short h, l; splitbf(s, h, l);
            WfTh[t * 128 + k] = h; WfTl[t * 128 + k] = l;
        } else {
            float s = 0.0f;
            #pragma unroll 8
            for (int j = 0; j < 128; j++) s = fmaf(b2[j], in_proj[j * 256 + t], s);
            bfv[t] = s;
        }
    } else if (blk < 642) {
        int idx = (blk - 513) * 256 + t;
        if (idx < BN_ * 3) out[(size_t)BN_ * D_ + idx] = pos[idx];
        if (idx < BN_) out[(size_t)BN_ * D_ + BN_ * 3 + idx] = (float)mi[idx];
    } else if (blk < 2690) {
        int rblk = blk - 642;
        int wv = t >> 6, ln = t & 63;
        int row = rblk * 4 + wv;
        const float2* xr = reinterpret_cast<const float2*>(x) + (size_t)row * 64;
        float2 v = xr[ln];
        float s = fmaf(v.x, v.x, v.y * v.y);
        #pragma unroll
        for (int o = 32; o > 0; o >>= 1) s += __shfl_down(s, o, 64);
        float tot = __shfl(s, 0, 64);
        float r = rsqrtf(tot * (1.0f / D_) + 1e-5f);
        float2 wv2 = reinterpret_cast<const float2*>(norm_w)[ln];
        float o0 = v.x * r * wv2.x, o1 = v.y * r * wv2.y;
        reinterpret_cast<float2*>(x1f)[(size_t)row * 64 + ln] = make_float2(o0, o1);
        unsigned short h0, l0, h1, l1;
        splitbf(o0, h0, l0); splitbf(o1, h1, l1);
        reinterpret_cast<ushort2*>(x1h)[(size_t)row * 64 + ln] = make_ushort2(h0, h1);
        reinterpret_cast<ushort2*>(x1l)[(size_t)row * 64 + ln] = make_ushort2(l0, l1);
    } else {
        __shared__ float px[N_], py[N_], pz[N_];
        __shared__ float lw[NG_];
        __shared__ int degs[8];
        int ablk = blk - 2690;
        int bx = ablk & 15, b = ablk >> 4;
        if (t < N_) {
            const float* p = pos + (size_t)(b * N_ + t) * 3;
            px[t] = p[0]; py[t] = p[1]; pz[t] = p[2];
        } else if (t - N_ < NG_) {
            lw[t - N_] = lin_w[t - N_];
        }
        if (t >= 248) degs[t - 248] = 0;
        __syncthreads();
        float linb = lin_b[0];
        int j = t & 127;
        int il = t >> 7;
        const float DEL = 10.0f / 49.0f;
        const float COEFF = -0.5f / (DEL * DEL);
        #pragma unroll
        for (int p = 0; p < 4; p++) {
            int i = bx * 8 + p * 2 + il;
            float dx = px[i] - px[j], dy = py[i] - py[j], dz = pz[i] - pz[j];
            float d2 = dx * dx + dy * dy + dz * dz;
            float dist = (i == j) ? 1.0f : sqrtf(d2);
            bool edge = (i != j) && (dist < CUTOFF_);
            float val = 0.0f;
            if (edge) {
                int g0 = (int)ceilf((dist - 1.75f) / DEL); if (g0 < 0) g0 = 0;
                int g1 = (int)floorf((dist + 1.75f) / DEL); if (g1 > NG_ - 1) g1 = NG_ - 1;
                float dm = dist - (float)g0 * DEL;
                float tg = expf(COEFF * dm * dm);
                float ug = expf(COEFF * DEL * (DEL - 2.0f * dm));
                float s = linb;
                for (int g = g0; g <= g1; g++) {
                    s = fmaf(lw[g], tg, s);
                    tg *= ug;
                    ug *= 0.36787944117144233f;   // e^{-1}
                }
                val = s;
            }
            size_t idx = ((size_t)b * N_ + i) * N_ + j;
            unsigned short h, l; splitbf(val, h, l);
            adjh[idx] = h; adjl[idx] = l;
            emh[idx] = edge ? 0x3F80 : 0;
            unsigned long long msk = __ballot(edge);
            if ((t & 63) == 0) atomicAdd(&degs[p * 2 + il], __popcll(msk));
        }
        __syncthreads();
        if (t < 8) {
            int dg = degs[t];
            rdeg[(size_t)b * N_ + bx * 8 + t] = 1.0f / (float)(dg > 0 ? dg : 1);
        }
    }
}

// ---------------------------------------------------------------------------
// Split-bf16 MFMA GEMM (proven).  32x64 tile, 4 waves, 48KB LDS.
#define AHOFF 0
#define ALOFF 8192
#define BHOFF 16384
#define BLOFF 32768
template <int EPI, bool ALO>
__global__ __launch_bounds__(256, 3) void mgemm_k(
        const unsigned short* __restrict__ Ah, const unsigned short* __restrict__ Al,
        const unsigned short* __restrict__ BTh, const unsigned short* __restrict__ BTl,
        const float* __restrict__ bias, const float* __restrict__ AUX,
        float* __restrict__ Cf, unsigned short* __restrict__ Ch,
        unsigned short* __restrict__ Cl, int cstride, int wbs) {
    extern __shared__ char sm[];
    int tid = threadIdx.x;
    int row_base = blockIdx.x * 32;
    int col_base = blockIdx.y * 64;

    const unsigned short* pBh = BTh;
    const unsigned short* pBl = BTl;
    if (wbs) {
        size_t bo = (size_t)(row_base >> 7) * (size_t)wbs;
        pBh += bo; pBl += bo;
    }

    #pragma unroll
    for (int i = 0; i < 2; i++) {
        int s = tid + i * 256;
        int row = s >> 4, inner = s & 15;
        int gb = (inner * 16) ^ ((row & 7) << 4);
        size_t gsrc = (size_t)(row_base + row) * 256 + gb;
        gl_lds((const char*)Ah + gsrc, sm + AHOFF + s * 16);
        if (ALO) gl_lds((const char*)Al + gsrc, sm + ALOFF + s * 16);
    }
    #pragma unroll
    for (int i = 0; i < 4; i++) {
        int s = tid + i * 256;
        int n = s >> 4, inner = s & 15;
        int gb = (inner * 16) ^ ((n & 7) << 4);
        size_t gsrc = (size_t)(col_base + n) * 256 + gb;
        gl_lds((const char*)pBh + gsrc, sm + BHOFF + s * 16);
        gl_lds((const char*)pBl + gsrc, sm + BLOFF + s * 16);
    }
    __syncthreads();

    int w = tid >> 6, l = tid & 63;
    int rlow = l & 15, kb_lane = (l >> 4) * 16;
    int nB = w * 16 + rlow;
    int nswz = (nB & 7) << 4;
    f32x4 acc[2] = {{0.f, 0.f, 0.f, 0.f}, {0.f, 0.f, 0.f, 0.f}};
    #pragma unroll
    for (int kb = 0; kb < 4; kb++) {
        int kbyte = kb * 64 + kb_lane;
        short8v bh = *(const short8v*)(sm + BHOFF + nB * 256 + (kbyte ^ nswz));
        short8v bl = *(const short8v*)(sm + BLOFF + nB * 256 + (kbyte ^ nswz));
        #pragma unroll
        for (int rf = 0; rf < 2; rf++) {
            int ra = rf * 16 + rlow;
            int aswz = (ra & 7) << 4;
            short8v ah = *(const short8v*)(sm + AHOFF + ra * 256 + (kbyte ^ aswz));
            acc[rf] = MFMA16(ah, bh, acc[rf], 0, 0, 0);
            acc[rf] = MFMA16(ah, bl, acc[rf], 0, 0, 0);
            if (ALO) {
                short8v al_ = *(const short8v*)(sm + ALOFF + ra * 256 + (kbyte ^ aswz));
                acc[rf] = MFMA16(al_, bh, acc[rf], 0, 0, 0);
            }
        }
    }

    int colg = col_base + w * 16 + rlow;
    #pragma unroll
    for (int rf = 0; rf < 2; rf++) {
        int row0 = row_base + rf * 16 + (l >> 4) * 4;
        if (EPI == 1) {
            float b_ = bias[colg];
            unsigned short hh[4], ll[4];
            #pragma unroll
            for (int q = 0; q < 4; q++) {
                float t = fmaxf(acc[rf][q] + b_, 0.0f);
                splitbf(t, hh[q], ll[q]);
            }
            size_t bb = (size_t)(row0 >> 7) * 16384 + (size_t)colg * 128 + (row0 & 127);
            *reinterpret_cast<ushort4*>(Ch + bb) = make_ushort4(hh[0], hh[1], hh[2], hh[3]);
            *reinterpret_cast<ushort4*>(Cl + bb) = make_ushort4(ll[0], ll[1], ll[2], ll[3]);
        } else {
            #pragma unroll
            for (int q = 0; q < 4; q++) {
                int row = row0 + q;
                float t = acc[rf][q];
                if (EPI == 2) {
                    t *= AUX[row];
                    unsigned short h, lo; splitbf(t, h, lo);
                    Ch[(size_t)row * 128 + colg] = h;
                    Cl[(size_t)row * 128 + colg] = lo;
                }
                if (EPI == 5) {
                    t = isfinite(t) ? t : 0.0f;
                    t += AUX[(size_t)row * 128 + colg];
                    Cf[(size_t)row * cstride + colg] = t;
                }
            }
        }
    }
}

// ---------------------------------------------------------------------------
// fused_k staging/GEMM helpers (512 threads)
__device__ __forceinline__ void st128(char* dst, const char* g, int tid) {
    #pragma unroll
    for (int i = 0; i < 4; i++) {
        int s = tid + i * 512;
        int row = s >> 4, inner = s & 15;
        gl_lds(g + row * 256 + ((inner * 16) ^ ((row & 7) << 4)), dst + s * 16);
    }
}
__device__ __forceinline__ void stA48(char* dst, const char* g, int r0, int tid) {
    #pragma unroll
    for (int i = 0; i < 2; i++) {
        int s = tid + i * 512;
        if (s < 768) {
            int lr = s >> 4, inner = s & 15;
            int srow = r0 - 16 + lr; if (srow < 0) srow = 0;
            gl_lds(g + srow * 256 + ((inner * 16) ^ ((lr & 7) << 4)), dst + s * 16);
        }
    }
}
template <int NRF>
__device__ __forceinline__ void fpass(const char* sm, int ah, int al, int bh, int bl,
                                      int w, int l, f32x4 (&acc)[NRF]) {
    int rlow = l & 15, khi = (l >> 4) * 16;
    int nB = w * 16 + rlow;
    int nkey = (nB & 7) << 4;
    #pragma unroll
    for (int kb = 0; kb < 4; kb++) {
        int kbyte = kb * 64 + khi;
        short8v bhv = *(const short8v*)(sm + bh + nB * 256 + (kbyte ^ nkey));
        short8v blv = *(const short8v*)(sm + bl + nB * 256 + (kbyte ^ nkey));
        #pragma unroll
        for (int rf = 0; rf < NRF; rf++) {
            int ra = rf * 16 + rlow;
            int ao = ra * 256 + (kbyte ^ ((ra & 7) << 4));
            short8v ahv = *(const short8v*)(sm + ah + ao);
            short8v alv = *(const short8v*)(sm + al + ao);
            acc[rf] = MFMA16(ahv, bhv, acc[rf], 0, 0, 0);
            acc[rf] = MFMA16(ahv, blv, acc[rf], 0, 0, 0);
            acc[rf] = MFMA16(alv, bhv, acc[rf], 0, 0, 0);
        }
    }
}

// ---------------------------------------------------------------------------
// fused_k: per (batch, 32-row group): xr GEMM, conv1d+silu+bc, delta GEMM,
// dp GEMM.  grid 256 x 512, 160KB LDS.
__global__ __launch_bounds__(512, 2) void fused_k(
        const unsigned short* __restrict__ aggh, const unsigned short* __restrict__ aggl,
        const unsigned short* __restrict__ WfTh, const unsigned short* __restrict__ WfTl,
        const float* __restrict__ bfv,
        const float* __restrict__ conv_w, const float* __restrict__ conv_b,
        const float* __restrict__ xpw,
        const unsigned short* __restrict__ WdTh, const unsigned short* __restrict__ WdTl,
        const float* __restrict__ dtb,
        const unsigned short* __restrict__ adjh, const unsigned short* __restrict__ adjl,
        float* __restrict__ resT, float* __restrict__ xcT,
        float* __restrict__ bcT, float* __restrict__ dpT) {
    __shared__ __align__(16) char sm[163840];
    const int AH = 0, AL = 12288, XM = 24576, BH = 49152, BL = 81920,
              XCH = 114688, XCL = 122880, DH = 131072, DL = 139264, XCF = 147456;
    int blk = blockIdx.x, tid = threadIdx.x;
    int b = blk >> 2, r0 = (blk & 3) * 32;
    int w = tid >> 6, l = tid & 63;
    int rlow = l & 15, qrow = (l >> 4) * 4;

    stA48(sm + AH, (const char*)aggh + (size_t)b * 32768, r0, tid);
    stA48(sm + AL, (const char*)aggl + (size_t)b * 32768, r0, tid);
    st128(sm + BH, (const char*)WfTh, tid);
    st128(sm + BL, (const char*)WfTl, tid);
    __syncthreads();

    f32x4 acc[3] = {{0.f,0.f,0.f,0.f},{0.f,0.f,0.f,0.f},{0.f,0.f,0.f,0.f}};
    fpass<3>(sm, AH, AL, BH, BL, w, l, acc);
    __syncthreads();
    st128(sm + BH, (const char*)WfTh + 32768, tid);
    st128(sm + BL, (const char*)WfTl + 32768, tid);
    {
        int colg = w * 16 + rlow;
        float bb = bfv[colg];
        #pragma unroll
        for (int rf = 0; rf < 3; rf++) {
            #pragma unroll
            for (int q = 0; q < 4; q++) {
                int lr = rf * 16 + qrow + q;
                *(float*)(sm + XM + lr * 512 + ((colg * 4) ^ ((lr & 7) << 4))) =
                    acc[rf][q] + bb;
            }
        }
    }
    __syncthreads();

    f32x4 acc2[3] = {{0.f,0.f,0.f,0.f},{0.f,0.f,0.f,0.f},{0.f,0.f,0.f,0.f}};
    fpass<3>(sm, AH, AL, BH, BL, w, l, acc2);
    {
        int colg = w * 16 + rlow;
        float bb = bfv[128 + colg];
        #pragma unroll
        for (int rf = 1; rf < 3; rf++) {
            int lr0 = rf * 16 + qrow;
            int tt = r0 + lr0 - 16;
            float v[4];
            #pragma unroll
            for (int q = 0; q < 4; q++) {
                float rs = acc2[rf][q] + bb;
                v[q] = rs / (1.0f + expf(-rs));
            }
            *reinterpret_cast<float4*>(resT + ((size_t)b * 128 + colg) * 128 + tt) =
                make_float4(v[0], v[1], v[2], v[3]);
        }
    }
    __syncthreads();

    st128(sm + BH, (const char*)WdTh, tid);
    st128(sm + BL, (const char*)WdTl, tid);
    {
        int ot = tid >> 4, dg = tid & 15;
        float pc0 = 0, pc1 = 0, pc2 = 0, pc3 = 0;
        #pragma unroll
        for (int k = 0; k < 8; k++) {
            int d = dg * 8 + k;
            float accv = conv_b[d];
            #pragma unroll
            for (int jj = 0; jj < 4; jj++) {
                int tt = r0 + ot + jj - 3;
                if (tt >= 0) {
                    int lr = ot + jj - 3 + 16;
                    float xv = *(const float*)(sm + XM + lr * 512 +
                                               ((d * 4) ^ ((lr & 7) << 4)));
                    accv = fmaf(xv, conv_w[d * 4 + jj], accv);
                }
            }
            float xc = accv / (1.0f + expf(-accv));   // silu
            unsigned short hh, ll; splitbf(xc, hh, ll);
            int pb = ot * 256 + ((d * 2) ^ ((ot & 7) << 4));
            *(unsigned short*)(sm + XCH + pb) = hh;
            *(unsigned short*)(sm + XCL + pb) = ll;
            *(float*)(sm + XCF + ot * 512 + ((d * 4) ^ ((ot & 7) << 4))) = xc;
            float4 xw = *(const float4*)(xpw + d * 12 + 8);
            pc0 = fmaf(xc, xw.x, pc0); pc1 = fmaf(xc, xw.y, pc1);
            pc2 = fmaf(xc, xw.z, pc2); pc3 = fmaf(xc, xw.w, pc3);
        }
        #pragma unroll
        for (int m = 1; m < 16; m <<= 1) {
            pc0 += __shfl_xor(pc0, m, 64);
            pc1 += __shfl_xor(pc1, m, 64);
            pc2 += __shfl_xor(pc2, m, 64);
            pc3 += __shfl_xor(pc3, m, 64);
        }
        if (dg < 4) {
            float pv = dg == 0 ? pc0 : dg == 1 ? pc1 : dg == 2 ? pc2 : pc3;
            bcT[(size_t)b * 512 + dg * 128 + r0 + ot] = pv;
        }
    }
    __syncthreads();

    {
        int d = tid & 127, tg = tid >> 7;
        float v[8];
        #pragma unroll
        for (int k = 0; k < 8; k++) {
            int ot = tg * 8 + k;
            v[k] = *(const float*)(sm + XCF + ot * 512 + ((d * 4) ^ ((ot & 7) << 4)));
        }
        float* dst = xcT + ((size_t)b * 128 + d) * 128 + r0 + tg * 8;
        *reinterpret_cast<float4*>(dst) = make_float4(v[0], v[1], v[2], v[3]);
        *reinterpret_cast<float4*>(dst + 4) = make_float4(v[4], v[5], v[6], v[7]);
    }

    f32x4 dacc[2] = {{0.f,0.f,0.f,0.f},{0.f,0.f,0.f,0.f}};
    fpass<2>(sm, XCH, XCL, BH, BL, w, l, dacc);
    {
        int colg = w * 16 + rlow;
        float db = dtb[colg];
        #pragma unroll
        for (int rf = 0; rf < 2; rf++) {
            #pragma unroll
            for (int q = 0; q < 4; q++) {
                int lr = rf * 16 + qrow + q;
                float t = dacc[rf][q] + db;
                t = fmaxf(t, 0.0f) + log1pf(expf(-fabsf(t)));
                unsigned short hh, ll; splitbf(t, hh, ll);
                int pb = lr * 256 + ((colg * 2) ^ ((lr & 7) << 4));
                *(unsigned short*)(sm + DH + pb) = hh;
                *(unsigned short*)(sm + DL + pb) = ll;
            }
        }
    }
    __syncthreads();

    st128(sm + BH, (const char*)adjh + (size_t)b * 32768, tid);
    st128(sm + BL, (const char*)adjl + (size_t)b * 32768, tid);
    __syncthreads();
    f32x4 pacc[2] = {{0.f,0.f,0.f,0.f},{0.f,0.f,0.f,0.f}};
    fpass<2>(sm, DH, DL, BH, BL, w, l, pacc);
    {
        int colg = w * 16 + rlow;
        #pragma unroll
        for (int rf = 0; rf < 2; rf++) {
            int lr0 = rf * 16 + qrow;
            *reinterpret_cast<float4*>(dpT + ((size_t)b * 128 + colg) * 128 + r0 + lr0) =
                make_float4(pacc[rf][0], pacc[rf][1], pacc[rf][2], pacc[rf][3]);
        }
    }
}

// ---------------------------------------------------------------------------
// scanout_k: shfl-free chunked LDS scan + fused out-GEMM (proven R17).
__global__ __launch_bounds__(256) void scanout_k(
        const float* __restrict__ dpT, const float* __restrict__ xcT,
        const float* __restrict__ bcT, const float* __restrict__ resT,
        const float* __restrict__ A_log, const float* __restrict__ Dpar,
        const unsigned short* __restrict__ opTh, const unsigned short* __restrict__ opTl,
        const float* __restrict__ x1f, float* __restrict__ out) {
    __shared__ __align__(16) char smb[116736];
    float* lds = (float*)smb;
    float* bcl = (float*)(smb + 49152);
    const int YH = 51200, YL = 83968;
    int b = blockIdx.x;
    int t = threadIdx.x;
    if (t < 128) {
        float4 v = reinterpret_cast<const float4*>(bcT + (size_t)b * 512)[t];
        *reinterpret_cast<float4*>(bcl + t * 4) = v;
    }
    float a1 = 0.f, a2 = 0.f, Dp = 0.f;
    if (t < 128) {
        a1 = -expf(A_log[t * 2]);
        a2 = -expf(A_log[t * 2 + 1]);
        Dp = Dpar[t];
    }
    float h1 = 0.0f, h2 = 0.0f;
    const float4* dp4 = reinterpret_cast<const float4*>(dpT + (size_t)b * 16384);
    const float4* xc4 = reinterpret_cast<const float4*>(xcT + (size_t)b * 16384);
    const float4* rr4 = reinterpret_cast<const float4*>(resT + (size_t)b * 16384);
    for (int c = 0; c < 4; c++) {
        __syncthreads();
        #pragma unroll
        for (int k = 0; k < 4; k++) {
            int q = t + k * 256;
            int dd = q >> 3, tq = q & 7;
            int gidx = dd * 32 + c * 8 + tq;
            float4 vd = dp4[gidx], vx = xc4[gidx], vr = rr4[gidx];
            #pragma unroll
            for (int j = 0; j < 4; j++) {
                int tp = tq * 4 + j;
                int sw = dd ^ tp;
                float fd = (j == 0) ? vd.x : (j == 1) ? vd.y : (j == 2) ? vd.z : vd.w;
                float fx = (j == 0) ? vx.x : (j == 1) ? vx.y : (j == 2) ? vx.z : vx.w;
                float fr = (j == 0) ? vr.x : (j == 1) ? vr.y : (j == 2) ? vr.z : vr.w;
                lds[tp * 128 + sw] = fd;
                lds[4096 + tp * 128 + sw] = fx;
                lds[8192 + tp * 128 + sw] = fr;
            }
        }
        __syncthreads();
        if (t < 128) {
            #pragma unroll 8
            for (int tp = 0; tp < 32; tp++) {
                int sw = t ^ tp;
                float dpv = lds[tp * 128 + sw];
                float xcv = lds[4096 + tp * 128 + sw];
                float rv  = lds[8192 + tp * 128 + sw];
                int tg = c * 32 + tp;
                float bm0 = bcl[tg], bm1 = bcl[128 + tg];
                float cm0 = bcl[256 + tg], cm1 = bcl[384 + tg];
                float e1 = expf(dpv * a1), e2 = expf(dpv * a2);
                float bu = dpv * xcv;
                h1 = fmaf(e1, h1, bu * bm0);
                h2 = fmaf(e2, h2, bu * bm1);
                float y = fmaf(h1, cm0, h2 * cm1);
                float yv = fmaf(xcv, Dp, y) * rv;
                unsigned short hh, ll; splitbf(yv, hh, ll);
                int byo = (t * 2) ^ ((tg & 7) << 4);
                *(unsigned short*)(smb + YH + tg * 256 + byo) = hh;
                *(unsigned short*)(smb + YL + tg * 256 + byo) = ll;
            }
        }
    }
    __syncthreads();

    int w = t >> 6, l = t & 63;
    int rlow = l & 15, kb_lane = (l >> 4) * 16;
    int nB = w * 16 + rlow;
    int nswz = (nB & 7) << 4;
    for (int cu = 0; cu < 2; cu++) {
        #pragma unroll
        for (int i = 0; i < 4; i++) {
            int s = t + i * 256;
            int row = s >> 4, inner = s & 15;
            int gb = (inner * 16) ^ ((row & 7) << 4);
            size_t gsrc = (size_t)(cu * 64 + row) * 256 + gb;
            gl_lds((const char*)opTh + gsrc, smb + s * 16);
            gl_lds((const char*)opTl + gsrc, smb + 16384 + s * 16);
        }
        __syncthreads();
        int colg = cu * 64 + nB;
        for (int ru = 0; ru < 4; ru++) {
            f32x4 acc[2] = {{0.f, 0.f, 0.f, 0.f}, {0.f, 0.f, 0.f, 0.f}};
            #pragma unroll
            for (int kb = 0; kb < 4; kb++) {
                int kbyte = kb * 64 + kb_lane;
                short8v bh = *(const short8v*)(smb + nB * 256 + (kbyte ^ nswz));
                short8v bl = *(const short8v*)(smb + 16384 + nB * 256 + (kbyte ^ nswz));
                #pragma unroll
                for (int rf = 0; rf < 2; rf++) {
                    int ra = ru * 32 + rf * 16 + rlow;
                    int aswz = (ra & 7) << 4;
                    short8v ah = *(const short8v*)(smb + YH + ra * 256 + (kbyte ^ aswz));
                    acc[rf] = MFMA16(ah, bh, acc[rf], 0, 0, 0);
                    acc[rf] = MFMA16(ah, bl, acc[rf], 0, 0, 0);
                    short8v al_ = *(const short8v*)(smb + YL + ra * 256 + (kbyte ^ aswz));
                    acc[rf] = MFMA16(al_, bh, acc[rf], 0, 0, 0);
                }
            }
            #pragma unroll
            for (int rf = 0; rf < 2; rf++) {
                int row0 = ru * 32 + rf * 16 + (l >> 4) * 4;
                #pragma unroll
                for (int q = 0; q < 4; q++) {
                    int row = row0 + q;
                    float tv = acc[rf][q];
                    tv = isfinite(tv) ? tv : 0.0f;
                    size_t g = (size_t)(b * 128 + row) * 128 + colg;
                    out[g] = tv + x1f[g];
                }
            }
        }
        __syncthreads();
    }
}

// ---------------------------------------------------------------------------
extern "C" void kernel_launch(void* const* d_in, const int* in_sizes, int n_in,
                              void* d_out, int out_size, void* d_ws, size_t ws_size,
                              hipStream_t stream) {
    const float* x        = (const float*)d_in[0];
    const float* pos      = (const float*)d_in[1];
    const int*   mi       = (const int*)d_in[2];
    const float* norm_w   = (const float*)d_in[4];
    const float* w1       = (const float*)d_in[5];
    const float* b1       = (const float*)d_in[6];
    const float* w2       = (const float*)d_in[7];
    const float* b2       = (const float*)d_in[8];
    const float* lin_w    = (const float*)d_in[9];
    const float* lin_b    = (const float*)d_in[10];
    const float* in_proj  = (const float*)d_in[11];
    const float* conv_w   = (const float*)d_in[12];
    const float* conv_b   = (const float*)d_in[13];
    const float* xpw      = (const float*)d_in[14];
    const float* dtw      = (const float*)d_in[15];
    const float* dtb      = (const float*)d_in[16];
    const float* A_log    = (const float*)d_in[17];
    const float* Dpar     = (const float*)d_in[18];
    const float* out_proj = (const float*)d_in[19];

    float* out = (float*)d_out;
    char* base = (char*)d_ws;
    const size_t MB = 1u << 20;
    const size_t PL = 1048576;            // elements per bf16 plane

    float* x1f  = (float*)(base);                      // 4MB
    float* resT = (float*)(base + 8 * MB);             // 4MB  [b][d][t]
    float* dpT  = (float*)(base + 12 * MB);            // 4MB  [b][d][t]
    float* xcT  = (float*)(base + 16 * MB);            // 4MB  [b][d][t]
    float* bcT  = (float*)(base + 20 * MB);            // 128KB [b][4][t]
    float* rdeg = (float*)(base + 20 * MB + 131072);   // 32KB

    unsigned short* P = (unsigned short*)(base + 21 * MB);
    unsigned short* x1h  = P +  0 * PL;
    unsigned short* x1l  = P +  1 * PL;
    unsigned short* hTh  = P +  2 * PL;   // [b][n][k]
    unsigned short* hTl  = P +  3 * PL;
    unsigned short* aggh = P +  4 * PL;
    unsigned short* aggl = P +  5 * PL;
    unsigned short* xch  = P +  6 * PL;
    unsigned short* xcl  = P +  7 * PL;
    unsigned short* dlh  = P +  8 * PL;
    unsigned short* dll  = P +  9 * PL;
    unsigned short* adjh = P + 12 * PL;   // symmetric => also B^T
    unsigned short* adjl = P + 13 * PL;
    unsigned short* emh  = P + 14 * PL;

    unsigned short* W = (unsigned short*)(base + 52 * MB);
    unsigned short* w1Th = W;
    unsigned short* w1Tl = W + 16384;
    unsigned short* WdTh = W + 2 * 16384;
    unsigned short* WdTl = W + 3 * 16384;
    unsigned short* opTh = W + 4 * 16384;
    unsigned short* opTl = W + 5 * 16384;
    unsigned short* WfTh = W + 6 * 16384;          // [256][128]
    unsigned short* WfTl = WfTh + 32768;
    float* bfv = (float*)(WfTl + 32768);

    const size_t gsm = 49152;   // 48KB

    // 1. setup: weights + copy + rmsnorm + adjacency
    setup_k<<<3714, 256, 0, stream>>>(x, norm_w, pos, mi, lin_w, lin_b,
                                      w1, w2, b2, in_proj, xpw, dtw, out_proj,
                                      w1Th, w1Tl, WdTh, WdTl, opTh, opTl, WfTh, WfTl,
                                      bfv, x1f, x1h, x1l, adjh, adjl, emh, rdeg, out);
    // 2. h = relu(x1 @ w1 + b1) -> hT planes
    mgemm_k<1, true><<<dim3(256, 2), 256, gsm, stream>>>(
        x1h, x1l, w1Th, w1Tl, b1, nullptr, nullptr, hTh, hTl, 128, 0);
    // 3. agg = (em @ h[b]) * rdeg -> planes
    mgemm_k<2, false><<<dim3(256, 2), 256, gsm, stream>>>(
        emh, emh, hTh, hTl, nullptr, rdeg, nullptr, aggh, aggl, 128, 16384);
    // 4. fused middle: xr + conv/silu/bc + delta + dp
    fused_k<<<256, 512, 0, stream>>>(aggh, aggl, WfTh, WfTl, bfv,
                                     conv_w, conv_b, xpw, WdTh, WdTl, dtb,
                                     adjh, adjl, resT, xcT, bcT, dpT);
    // 5. scan + fused out-GEMM -> d_out
    scanout_k<<<B_, 256, 0, stream>>>(dpT, xcT, bcT, resT, A_log, Dpar,
                                      opTh, opTl, x1f, out);
}